// Round 2
// baseline (2998.417 us; speedup 1.0000x reference)
//
#include <hip/hip_runtime.h>
#include <math.h>

#define Nn   1023
#define Hdim 512

__device__ __forceinline__ float sigf(float x) { return 1.0f / (1.0f + __expf(-x)); }

// ---------------------------------------------------------------------------
// Pack effective weights: Wpack[k][g2], k in [0,1536), g2 = q*512 + j.
// Effective gate row in original 8H layout: q*1024 + j (first H of each 2H gate).
// k<512 -> W_ih[row][k]; k>=512 -> W_hh[row][k-512].
// ---------------------------------------------------------------------------
__global__ __launch_bounds__(256) void pack_w(const float* __restrict__ W_ih,
                                              const float* __restrict__ W_hh,
                                              float* __restrict__ Wpack) {
    __shared__ float tile[64][65];
    int g2base = blockIdx.x * 64;   // 32 blocks
    int kbase  = blockIdx.y * 64;   // 24 blocks
    int t = threadIdx.x;
    #pragma unroll
    for (int i = 0; i < 16; ++i) {
        int idx = t + i * 256;
        int lg = idx >> 6, lk = idx & 63;
        int g2 = g2base + lg;
        int row = ((g2 >> 9) << 10) + (g2 & 511);
        int k = kbase + lk;
        float v = (k < 512) ? W_ih[row * 512 + k] : W_hh[row * 1024 + (k - 512)];
        tile[lg][lk] = v;
    }
    __syncthreads();
    #pragma unroll
    for (int i = 0; i < 16; ++i) {
        int idx = t + i * 256;
        int lk = idx >> 6, lg = idx & 63;
        Wpack[(size_t)(kbase + lk) * 2048 + g2base + lg] = tile[lg][lk];
    }
}

// W1 (512x512 row-major [j][k]) -> W1t[k][j]
__global__ __launch_bounds__(256) void transpose512(const float* __restrict__ W1,
                                                    float* __restrict__ W1t) {
    __shared__ float tile[64][65];
    int jb = blockIdx.x * 64, kb = blockIdx.y * 64;
    int t = threadIdx.x;
    #pragma unroll
    for (int i = 0; i < 16; ++i) {
        int idx = t + i * 256;
        int lj = idx >> 6, lk = idx & 63;
        tile[lj][lk] = W1[(jb + lj) * 512 + kb + lk];
    }
    __syncthreads();
    #pragma unroll
    for (int i = 0; i < 16; ++i) {
        int idx = t + i * 256;
        int lk = idx >> 6, lj = idx & 63;
        W1t[(kb + lk) * 512 + jb + lj] = tile[lj][lk];
    }
}

// bias_eff[g2] = b_ih[row]+b_hh[row]; W2t[k][op] = W2[op][k]
__global__ __launch_bounds__(256) void small_prep(const float* __restrict__ b_ih,
                                                  const float* __restrict__ b_hh,
                                                  float* __restrict__ bias_eff,
                                                  const float* __restrict__ W2,
                                                  float* __restrict__ W2t) {
    int t = blockIdx.x * 256 + threadIdx.x;  // 32 blocks -> 8192 threads
    if (t < 2048) {
        int row = ((t >> 9) << 10) + (t & 511);
        bias_eff[t] = b_ih[row] + b_hh[row];
    }
    if (t < 8192) {
        int k = t >> 4, op = t & 15;
        W2t[t] = W2[op * 512 + k];
    }
}

// Fallback when ws_size is insufficient: deterministic zero output (clean
// "incorrect" instead of an OOB write that can kill the container).
__global__ void zero_out(float* __restrict__ outp, int n) {
    int i = blockIdx.x * 256 + threadIdx.x;
    if (i < n) outp[i] = 0.f;
}

// ---------------------------------------------------------------------------
// One tree level: rows = nloc*64 (row = local*64 + b), gates g2 = q*512+j.
// A[row, k] = k<512 ? emb(gathered, last-elem override) : h_child.
// Block tile: 64 rows (= one node, all 64 batches) x 64 j-cols x 4 gates.
// c is stored ONLY for even locals (left children), at index (local>>1):
// right-children's c is provably dead (c_new[:H] uses c[left] only).
// ---------------------------------------------------------------------------
__global__ __launch_bounds__(256) void lstm_level(
    const float* __restrict__ Wpack, const float* __restrict__ bias_eff,
    const int* __restrict__ node_types, const float* __restrict__ node_args,
    const float* __restrict__ emb_table,
    const float* __restrict__ in_h, const float* __restrict__ in_c,
    float* __restrict__ out_h, float* __restrict__ out_c,
    int base, int K) {
    __shared__ __attribute__((aligned(16))) float As[16][64];
    __shared__ __attribute__((aligned(16))) float Ws[16][256];
    int t = threadIdx.x;
    int local = blockIdx.x;       // node index within level == row tile
    int j0 = blockIdx.y * 64;
    int tr = t & 15, tc = t >> 4;

    float acc[4][4][4] = {};      // [gate q][row ri][col ji]

    // staging ids: each thread loads 4 consecutive k for one row
    int srow = t & 63;            // == batch b
    int kq4 = (t >> 6) * 4;       // 0,4,8,12

    int b = srow;
    int node = base + local;
    int ty = node_types[b * Nn + node];
    const float4* embrow = (const float4*)(emb_table + (size_t)ty * 512);
    float argv = node_args[b * Nn + node];
    bool isint = (ty <= 1);

    for (int kk0 = 0; kk0 < K; kk0 += 16) {
        __syncthreads();
        // stage A (16 k x 64 rows)
        {
            int kg = kk0 + kq4;
            float4 v;
            if (kg < 512) {
                v = embrow[kg >> 2];
                if (isint && kg == 508) v.w = argv;  // emb[..., 511] override
            } else {
                int kh = kg - 512;
                int child = (kh < 512) ? (2 * local) : (2 * local + 1);
                int koff = kh & 511;
                v = *(const float4*)(in_h + ((size_t)(child * 64 + b)) * 512 + koff);
            }
            As[kq4 + 0][srow] = v.x;
            As[kq4 + 1][srow] = v.y;
            As[kq4 + 2][srow] = v.z;
            As[kq4 + 3][srow] = v.w;
        }
        // stage W (16 k x 4 gates x 64 j)
        {
            int lk = t >> 4, jq = t & 15;
            const float* wrow = Wpack + (size_t)(kk0 + lk) * 2048 + j0 + jq * 4;
            *(float4*)&Ws[lk][0 * 64 + jq * 4] = *(const float4*)(wrow + 0 * 512);
            *(float4*)&Ws[lk][1 * 64 + jq * 4] = *(const float4*)(wrow + 1 * 512);
            *(float4*)&Ws[lk][2 * 64 + jq * 4] = *(const float4*)(wrow + 2 * 512);
            *(float4*)&Ws[lk][3 * 64 + jq * 4] = *(const float4*)(wrow + 3 * 512);
        }
        __syncthreads();
        #pragma unroll
        for (int k = 0; k < 16; ++k) {
            float4 a = *(float4*)&As[k][tr * 4];
            float av[4] = {a.x, a.y, a.z, a.w};
            #pragma unroll
            for (int q = 0; q < 4; ++q) {
                float4 w = *(float4*)&Ws[k][q * 64 + tc * 4];
                float wv[4] = {w.x, w.y, w.z, w.w};
                #pragma unroll
                for (int ri = 0; ri < 4; ++ri)
                    #pragma unroll
                    for (int ji = 0; ji < 4; ++ji)
                        acc[q][ri][ji] = fmaf(av[ri], wv[ji], acc[q][ri][ji]);
            }
        }
    }

    // epilogue: LSTM cell, write h (all) / c (even locals only)
    bool write_c = ((local & 1) == 0);
    #pragma unroll
    for (int ri = 0; ri < 4; ++ri) {
        int bb = tr * 4 + ri;                 // batch
        int jg = j0 + tc * 4;
        float cl[4] = {0.f, 0.f, 0.f, 0.f};
        if (in_c) {
            // left child = 2*local (even) -> stored at index local
            float4 cl4 = *(const float4*)(in_c + ((size_t)(local * 64 + bb)) * 512 + jg);
            cl[0] = cl4.x; cl[1] = cl4.y; cl[2] = cl4.z; cl[3] = cl4.w;
        }
        float4 co, ho;
        float* cop = (float*)&co;
        float* hop = (float*)&ho;
        #pragma unroll
        for (int ji = 0; ji < 4; ++ji) {
            int j = jg + ji;
            float ig = acc[0][ri][ji] + bias_eff[j];
            float fg = acc[1][ri][ji] + bias_eff[512 + j];
            float gg = acc[2][ri][ji] + bias_eff[1024 + j];
            float og = acc[3][ri][ji] + bias_eff[1536 + j];
            float cn = sigf(fg) * cl[ji] + sigf(ig) * tanhf(gg);
            float hn = sigf(og) * tanhf(cn);
            cop[ji] = cn;
            hop[ji] = hn;
        }
        size_t orow = (size_t)(local * 64 + bb);
        if (write_c)
            *(float4*)(out_c + ((size_t)((local >> 1) * 64 + bb)) * 512 + jg) = co;
        *(float4*)(out_h + orow * 512 + jg) = ho;
    }
}

// ---------------------------------------------------------------------------
// Head: x = relu(root_h @ W1^T + b1); logits = x @ W2^T + b2 + log(vm);
// out = softmax(logits/3). One block per batch element.
// ---------------------------------------------------------------------------
__global__ __launch_bounds__(256) void head_kernel(
    const float* __restrict__ rootH, const float* __restrict__ W1t,
    const float* __restrict__ b1, const float* __restrict__ W2t,
    const float* __restrict__ b2, const float* __restrict__ vmask,
    float* __restrict__ outp) {
    __shared__ float rh[512];
    __shared__ float xs[512];
    __shared__ float part[16][17];
    int b = blockIdx.x, t = threadIdx.x;
    rh[t] = rootH[b * 512 + t];
    rh[t + 256] = rootH[b * 512 + t + 256];
    __syncthreads();
    #pragma unroll
    for (int jj = 0; jj < 2; ++jj) {
        int j = t + jj * 256;
        float acc = b1[j];
        for (int k = 0; k < 512; ++k) acc = fmaf(rh[k], W1t[k * 512 + j], acc);
        xs[j] = fmaxf(acc, 0.f);
    }
    __syncthreads();
    int op = t & 15, seg = t >> 4;
    float p = 0.f;
    for (int k = seg * 32; k < seg * 32 + 32; ++k) p = fmaf(xs[k], W2t[k * 16 + op], p);
    part[seg][op] = p;
    __syncthreads();
    if (t < 16) {
        float s = 0.f;
        #pragma unroll
        for (int g = 0; g < 16; ++g) s += part[g][t];
        float logit = s + b2[t] + logf(vmask[b * 16 + t]);
        float z = logit * (1.0f / 3.0f);
        float m = z;
        for (int off = 8; off; off >>= 1) m = fmaxf(m, __shfl_xor(m, off, 16));
        float e = __expf(z - m);
        float ssum = e;
        for (int off = 8; off; off >>= 1) ssum += __shfl_xor(ssum, off, 16);
        outp[b * 16 + t] = e / ssum;
    }
}

extern "C" void kernel_launch(void* const* d_in, const int* in_sizes, int n_in,
                              void* d_out, int out_size, void* d_ws, size_t ws_size,
                              hipStream_t stream) {
    const int*   node_types = (const int*)d_in[0];
    const float* node_args  = (const float*)d_in[1];
    const float* vmask      = (const float*)d_in[2];
    const float* emb_table  = (const float*)d_in[3];
    const float* W_ih       = (const float*)d_in[4];
    const float* W_hh       = (const float*)d_in[5];
    const float* b_ih       = (const float*)d_in[6];
    const float* b_hh       = (const float*)d_in[7];
    const float* W1         = (const float*)d_in[8];
    const float* b1         = (const float*)d_in[9];
    const float* W2         = (const float*)d_in[10];
    const float* b2         = (const float*)d_in[11];
    float* out = (float*)d_out;

    float* ws = (float*)d_ws;
    size_t off = 0;
    float* Wpack    = ws + off; off += (size_t)1536 * 2048;   // 12.6 MB
    float* bias_eff = ws + off; off += 2048;
    float* W1t      = ws + off; off += (size_t)512 * 512;     // 1 MB
    float* W2t      = ws + off; off += (size_t)512 * 16;
    float* Xh       = ws + off; off += (size_t)256 * 64 * 512; // 33.5 MB
    float* Xc       = ws + off; off += (size_t)128 * 64 * 512; // 16.8 MB (even locals only)
    float* Yh       = ws + off; off += (size_t)128 * 64 * 512; // 16.8 MB
    float* Yc       = ws + off; off += (size_t)64 * 64 * 512;  //  8.4 MB
    size_t needed_bytes = off * sizeof(float);                 // ~89 MB

    if (ws_size < needed_bytes) {
        // Not enough scratch: produce deterministic (wrong) zeros instead of
        // an OOB write. Signals "ws too small" without killing the container.
        zero_out<<<(out_size + 255) / 256, 256, 0, stream>>>(out, out_size);
        return;
    }

    pack_w<<<dim3(32, 24), 256, 0, stream>>>(W_ih, W_hh, Wpack);
    transpose512<<<dim3(8, 8), 256, 0, stream>>>(W1, W1t);
    small_prep<<<32, 256, 0, stream>>>(b_ih, b_hh, bias_eff, W2, W2t);

    for (int d = 8; d >= 0; --d) {
        int nloc = 1 << d;
        int base = nloc - 1;
        float* oh = (d & 1) ? Yh : Xh;
        float* oc = (d & 1) ? Yc : Xc;
        const float* ih = nullptr;
        const float* ic = nullptr;
        int K = 512;
        if (d < 8) {
            ih = (d & 1) ? Xh : Yh;
            ic = (d & 1) ? Xc : Yc;
            K = 1536;
        }
        lstm_level<<<dim3(nloc, 8), 256, 0, stream>>>(
            Wpack, bias_eff, node_types, node_args, emb_table,
            ih, ic, oh, oc, base, K);
    }

    head_kernel<<<64, 256, 0, stream>>>(Xh, W1t, b1, W2t, b2, vmask, out);
}

// Round 3
// 527.388 us; speedup vs baseline: 5.6854x; 5.6854x over previous
//
#include <hip/hip_runtime.h>
#include <math.h>

#define Nn 1023

typedef __attribute__((ext_vector_type(8))) short short8;
typedef __attribute__((ext_vector_type(4))) float f32x4;

#define AS1(p) ((const __attribute__((address_space(1))) void*)(p))
#define AS3(p) ((__attribute__((address_space(3))) void*)(p))

__device__ __forceinline__ float sigf(float x) { return 1.0f / (1.0f + __expf(-x)); }
__device__ __forceinline__ unsigned short f2bf(float x) {
    unsigned u = __float_as_uint(x);
    return (unsigned short)((u + 0x7fffu + ((u >> 16) & 1u)) >> 16);
}
__device__ __forceinline__ float bf2f(unsigned short b) {
    return __uint_as_float(((unsigned)b) << 16);
}

// ---------------------------------------------------------------------------
// Weight pack: WpT[P][k] bf16, P = jhi*64 + q*16 + jlo (gate-interleaved so a
// 16-col MFMA fragment column q holds gate q of j = jhi*16 + jlo).
// orig gate row = q*1024 + j (first H of each 2H gate; rest provably dead).
// k<512 -> W_ih[row][k]; k in [512,1536) -> W_hh[row][k-512] (hL then hR).
// ---------------------------------------------------------------------------
__global__ __launch_bounds__(256) void pack_wT(const float* __restrict__ W_ih,
                                               const float* __restrict__ W_hh,
                                               unsigned short* __restrict__ WpT) {
    int idx = blockIdx.x * 256 + threadIdx.x;   // 1536 blocks -> 393216 = 2048*192
    int P = idx / 192;
    int k0 = (idx % 192) * 8;
    int row = ((P >> 4) & 3) * 1024 + (P >> 6) * 16 + (P & 15);
    const float* src = (k0 < 512) ? (W_ih + (size_t)row * 512 + k0)
                                  : (W_hh + (size_t)row * 1024 + (k0 - 512));
    float4 v0 = *(const float4*)src;
    float4 v1 = *(const float4*)(src + 4);
    short8 o;
    o[0] = (short)f2bf(v0.x); o[1] = (short)f2bf(v0.y);
    o[2] = (short)f2bf(v0.z); o[3] = (short)f2bf(v0.w);
    o[4] = (short)f2bf(v1.x); o[5] = (short)f2bf(v1.y);
    o[6] = (short)f2bf(v1.z); o[7] = (short)f2bf(v1.w);
    *(short8*)(WpT + (size_t)P * 1536 + k0) = o;
}

// W1 (512x512 row-major [j][k]) -> W1t[k][j]  (fp32, head stays fp32)
__global__ __launch_bounds__(256) void transpose512(const float* __restrict__ W1,
                                                    float* __restrict__ W1t) {
    __shared__ float tile[64][65];
    int jb = blockIdx.x * 64, kb = blockIdx.y * 64;
    int t = threadIdx.x;
    #pragma unroll
    for (int i = 0; i < 16; ++i) {
        int idx = t + i * 256;
        int lj = idx >> 6, lk = idx & 63;
        tile[lj][lk] = W1[(jb + lj) * 512 + kb + lk];
    }
    __syncthreads();
    #pragma unroll
    for (int i = 0; i < 16; ++i) {
        int idx = t + i * 256;
        int lk = idx >> 6, lj = idx & 63;
        W1t[(kb + lk) * 512 + jb + lj] = tile[lj][lk];
    }
}

// bias_eff[P] (permuted like WpT rows), W2t[k][op], embt = bf16(emb_table)
__global__ __launch_bounds__(256) void small_prep(const float* __restrict__ b_ih,
                                                  const float* __restrict__ b_hh,
                                                  float* __restrict__ bias_eff,
                                                  const float* __restrict__ W2,
                                                  float* __restrict__ W2t,
                                                  const float* __restrict__ emb,
                                                  unsigned short* __restrict__ embt) {
    int t = blockIdx.x * 256 + threadIdx.x;  // 32 blocks -> 8192
    if (t < 2048) {
        int row = ((t >> 4) & 3) * 1024 + (t >> 6) * 16 + (t & 15);
        bias_eff[t] = b_ih[row] + b_hh[row];
    }
    if (t < 8192) {
        int k = t >> 4, op = t & 15;
        W2t[t] = W2[op * 512 + k];
        embt[t] = f2bf(emb[t]);
        embt[t + 8192] = f2bf(emb[t + 8192]);
    }
}

__global__ void zero_out(float* __restrict__ outp, int n) {
    int i = blockIdx.x * 256 + threadIdx.x;
    if (i < n) outp[i] = 0.f;
}

// ---------------------------------------------------------------------------
// One tree level, bf16 MFMA. Block: 128 rows (2 nodes x 64 batch) x 128 P-cols,
// 4 waves (2x2), wave tile 64x64, BK=64 (2 mfma K-steps), 2-barrier loop with
// global_load_lds width-16 staging. acc[mi][q]: q is the gate (pack order).
// A[r][k]: k<512 emb(ty)+arg-override@511 (LDS patch on kt==7); then hL, hR.
// c stored fp32 for even locals only at index local>>1 (right-c is dead).
// ---------------------------------------------------------------------------
template<bool LEAF>
__global__ __launch_bounds__(256) void lstm_mfma(
    const unsigned short* __restrict__ WpT, const float* __restrict__ bias_eff,
    const unsigned short* __restrict__ embt,
    const int* __restrict__ node_types, const float* __restrict__ node_args,
    const unsigned short* __restrict__ in_h, const float* __restrict__ in_c,
    unsigned short* __restrict__ out_h, float* __restrict__ out_c,
    int base, int nloc) {
    __shared__ __attribute__((aligned(16))) unsigned short AB[16384]; // A:8192, B:8192 shorts
    unsigned short* As = AB;
    unsigned short* Bs = AB + 8192;
    const int t = threadIdx.x;
    const int w = t >> 6, lane = t & 63;
    const int wr = w >> 1, wc = w & 1;
    const int lane15 = lane & 15, lg = lane >> 4;
    const int M = nloc * 64;
    const int brow0 = blockIdx.x * 128;
    const int bcol0 = blockIdx.y * 128;

    // per-q staging base pointers (lane-dependent row, fixed across K-loop)
    const char* eA[4];
    const char* hA[4];
    const char* wB[4];
    #pragma unroll
    for (int q = 0; q < 4; ++q) {
        int m = w * 32 + q * 8 + (lane >> 3);
        int r = brow0 + m; if (r > M - 1) r = M - 1;
        int local = r >> 6, b = r & 63;
        int node = base + local;
        int ty = node_types[b * Nn + node];
        eA[q] = (const char*)embt + (size_t)ty * 1024;
        if (!LEAF)
            hA[q] = (const char*)in_h + ((size_t)(local * 128 + b)) * 1024; // row (2*local)*64+b
        int P = bcol0 + w * 32 + q * 8 + (lane >> 3);
        wB[q] = (const char*)WpT + (size_t)P * 3072;
    }
    const int lanek16 = (lane & 7) * 16;

    // k=511 override data (one row per thread t<128)
    bool pint; unsigned short pargv;
    {
        int rp = brow0 + (t & 127); if (rp > M - 1) rp = M - 1;
        int local = rp >> 6, b = rp & 63;
        int node = base + local;
        pint = (node_types[b * Nn + node] <= 1);
        pargv = f2bf(node_args[b * Nn + node]);
    }

    float bz[4];
    #pragma unroll
    for (int q = 0; q < 4; ++q) bz[q] = bias_eff[bcol0 + wc * 64 + q * 16 + lane15];

    f32x4 acc[4][4] = {};

    const int NT = LEAF ? 8 : 24;
    for (int kt = 0; kt < NT; ++kt) {
        #pragma unroll
        for (int q = 0; q < 4; ++q) {
            const char* gA;
            if (LEAF) {
                gA = eA[q] + kt * 128 + lanek16;
            } else {
                if (kt < 8)       gA = eA[q] + kt * 128 + lanek16;
                else if (kt < 16) gA = hA[q] + (kt - 8) * 128 + lanek16;
                else              gA = hA[q] + 65536 + (kt - 16) * 128 + lanek16;
            }
            __builtin_amdgcn_global_load_lds(AS1(gA), AS3((char*)As + w * 4096 + q * 1024), 16, 0, 0);
            const char* gB = wB[q] + kt * 128 + lanek16;
            __builtin_amdgcn_global_load_lds(AS1(gB), AS3((char*)Bs + w * 4096 + q * 1024), 16, 0, 0);
        }
        __syncthreads();   // drains vmcnt -> LDS ready
        if (kt == 7) {     // patch emb element k=511 with node_args where is_int
            if (t < 128 && pint) As[t * 64 + 63] = (unsigned short)pargv;
            __syncthreads();
        }
        #pragma unroll
        for (int ks = 0; ks < 2; ++ks) {
            short8 av[4], bv[4];
            #pragma unroll
            for (int mi = 0; mi < 4; ++mi)
                av[mi] = *(const short8*)(As + (wr * 64 + mi * 16 + lane15) * 64 + ks * 32 + lg * 8);
            #pragma unroll
            for (int q = 0; q < 4; ++q)
                bv[q] = *(const short8*)(Bs + (wc * 64 + q * 16 + lane15) * 64 + ks * 32 + lg * 8);
            #pragma unroll
            for (int mi = 0; mi < 4; ++mi)
                #pragma unroll
                for (int q = 0; q < 4; ++q)
                    acc[mi][q] = __builtin_amdgcn_mfma_f32_16x16x32_bf16(av[mi], bv[q], acc[mi][q], 0, 0, 0);
        }
        __syncthreads();   // all waves done reading before next stage overwrites
    }

    // epilogue: per lane, acc[mi][0..3] = i,f,g,o gates of column j
    const int j = (blockIdx.y * 2 + wc) * 16 + lane15;
    #pragma unroll
    for (int mi = 0; mi < 4; ++mi) {
        int rbase = brow0 + wr * 64 + mi * 16 + lg * 4;
        #pragma unroll
        for (int reg = 0; reg < 4; ++reg) {
            int r = rbase + reg;
            if (r < M) {
                float ig = acc[mi][0][reg] + bz[0];
                float fg = acc[mi][1][reg] + bz[1];
                float gg = acc[mi][2][reg] + bz[2];
                float og = acc[mi][3][reg] + bz[3];
                float cl = 0.f;
                if (!LEAF) cl = in_c[(size_t)r * 512 + j];
                float cn = sigf(fg) * cl + sigf(ig) * tanhf(gg);
                float hn = sigf(og) * tanhf(cn);
                out_h[(size_t)r * 512 + j] = f2bf(hn);
                if (((r >> 6) & 1) == 0)  // even local: store c at local>>1
                    out_c[((size_t)((r >> 7) * 64 + (r & 63))) * 512 + j] = cn;
            }
        }
    }
}

// ---------------------------------------------------------------------------
// Head: x = relu(root_h @ W1^T + b1); logits = x @ W2^T + b2 + log(vm);
// out = softmax(logits/3). One block per batch element. rootH is bf16.
// ---------------------------------------------------------------------------
__global__ __launch_bounds__(256) void head_kernel(
    const unsigned short* __restrict__ rootH, const float* __restrict__ W1t,
    const float* __restrict__ b1, const float* __restrict__ W2t,
    const float* __restrict__ b2, const float* __restrict__ vmask,
    float* __restrict__ outp) {
    __shared__ float rh[512];
    __shared__ float xs[512];
    __shared__ float part[16][17];
    int b = blockIdx.x, t = threadIdx.x;
    rh[t] = bf2f(rootH[b * 512 + t]);
    rh[t + 256] = bf2f(rootH[b * 512 + t + 256]);
    __syncthreads();
    #pragma unroll
    for (int jj = 0; jj < 2; ++jj) {
        int j = t + jj * 256;
        float acc = b1[j];
        for (int k = 0; k < 512; ++k) acc = fmaf(rh[k], W1t[k * 512 + j], acc);
        xs[j] = fmaxf(acc, 0.f);
    }
    __syncthreads();
    int op = t & 15, seg = t >> 4;
    float p = 0.f;
    for (int k = seg * 32; k < seg * 32 + 32; ++k) p = fmaf(xs[k], W2t[k * 16 + op], p);
    part[seg][op] = p;
    __syncthreads();
    if (t < 16) {
        float s = 0.f;
        #pragma unroll
        for (int g = 0; g < 16; ++g) s += part[g][t];
        float logit = s + b2[t] + logf(vmask[b * 16 + t]);
        float z = logit * (1.0f / 3.0f);
        float m = z;
        for (int off = 8; off; off >>= 1) m = fmaxf(m, __shfl_xor(m, off, 16));
        float e = __expf(z - m);
        float ssum = e;
        for (int off = 8; off; off >>= 1) ssum += __shfl_xor(ssum, off, 16);
        outp[b * 16 + t] = e / ssum;
    }
}

extern "C" void kernel_launch(void* const* d_in, const int* in_sizes, int n_in,
                              void* d_out, int out_size, void* d_ws, size_t ws_size,
                              hipStream_t stream) {
    const int*   node_types = (const int*)d_in[0];
    const float* node_args  = (const float*)d_in[1];
    const float* vmask      = (const float*)d_in[2];
    const float* emb_table  = (const float*)d_in[3];
    const float* W_ih       = (const float*)d_in[4];
    const float* W_hh       = (const float*)d_in[5];
    const float* b_ih       = (const float*)d_in[6];
    const float* b_hh       = (const float*)d_in[7];
    const float* W1         = (const float*)d_in[8];
    const float* b1         = (const float*)d_in[9];
    const float* W2         = (const float*)d_in[10];
    const float* b2         = (const float*)d_in[11];
    float* out = (float*)d_out;

    char* ws = (char*)d_ws;
    size_t off = 0;
    auto alloc = [&](size_t bytes) { char* p = ws + off; off += (bytes + 255) & ~(size_t)255; return p; };
    unsigned short* WpT   = (unsigned short*)alloc((size_t)2048 * 1536 * 2); // 6.3 MB
    float* bias_eff       = (float*)alloc(2048 * 4);
    unsigned short* embt  = (unsigned short*)alloc(16384 * 2);
    float* W1t            = (float*)alloc((size_t)512 * 512 * 4);
    float* W2t            = (float*)alloc(8192 * 4);
    unsigned short* Xh    = (unsigned short*)alloc((size_t)256 * 64 * 512 * 2); // 16.8 MB
    unsigned short* Yh    = (unsigned short*)alloc((size_t)128 * 64 * 512 * 2); //  8.4 MB
    float* Xc             = (float*)alloc((size_t)128 * 64 * 512 * 4);          // 16.8 MB
    float* Yc             = (float*)alloc((size_t)64 * 64 * 512 * 4);           //  8.4 MB

    if (ws_size < off) {
        zero_out<<<(out_size + 255) / 256, 256, 0, stream>>>(out, out_size);
        return;
    }

    pack_wT<<<1536, 256, 0, stream>>>(W_ih, W_hh, WpT);
    transpose512<<<dim3(8, 8), 256, 0, stream>>>(W1, W1t);
    small_prep<<<32, 256, 0, stream>>>(b_ih, b_hh, bias_eff, W2, W2t, emb_table, embt);

    // leaf level d=8 (K=512, children are zero)
    lstm_mfma<true><<<dim3(128, 16), 256, 0, stream>>>(
        WpT, bias_eff, embt, node_types, node_args,
        nullptr, nullptr, Xh, Xc, 255, 256);

    for (int d = 7; d >= 0; --d) {
        int nloc = 1 << d;
        unsigned short* oh = (d & 1) ? Yh : Xh;
        float* oc          = (d & 1) ? Yc : Xc;
        const unsigned short* ih = (d & 1) ? Xh : Yh;
        const float* ic          = (d & 1) ? Xc : Yc;
        int gx = (nloc >= 2) ? (nloc / 2) : 1;
        lstm_mfma<false><<<dim3(gx, 16), 256, 0, stream>>>(
            WpT, bias_eff, embt, node_types, node_args,
            ih, ic, oh, oc, nloc - 1, nloc);
    }

    head_kernel<<<64, 256, 0, stream>>>(Xh, W1t, b1, W2t, b2, vmask, out);
}

// Round 4
// 514.087 us; speedup vs baseline: 5.8325x; 1.0259x over previous
//
#include <hip/hip_runtime.h>
#include <math.h>

#define Nn 1023

typedef __attribute__((ext_vector_type(8))) short short8;
typedef __attribute__((ext_vector_type(4))) float f32x4;

#define AS1(p) ((const __attribute__((address_space(1))) void*)(p))
#define AS3(p) ((__attribute__((address_space(3))) void*)(p))

__device__ __forceinline__ float sigf(float x) { return 1.0f / (1.0f + __expf(-x)); }
__device__ __forceinline__ unsigned short f2bf(float x) {
    unsigned u = __float_as_uint(x);
    return (unsigned short)((u + 0x7fffu + ((u >> 16) & 1u)) >> 16);
}
__device__ __forceinline__ float bf2f(unsigned short b) {
    return __uint_as_float(((unsigned)b) << 16);
}

// ---------------------------------------------------------------------------
// Weight pack (hh part only): WhT[P][k2] bf16, P = jhi*64 + q*16 + jlo,
// orig gate row = q*1024 + (jhi*16+jlo); k2 in [0,1024) -> W_hh[row][k2]
// (hL for k2<512, hR for k2>=512).
// ---------------------------------------------------------------------------
__global__ __launch_bounds__(256) void pack_whT(const float* __restrict__ W_hh,
                                                unsigned short* __restrict__ WhT) {
    int idx = blockIdx.x * 256 + threadIdx.x;   // 1024 blocks -> 262144 = 2048*128
    int P = idx >> 7;
    int k0 = (idx & 127) * 8;
    int row = ((P >> 4) & 3) * 1024 + (P >> 6) * 16 + (P & 15);
    const float* src = W_hh + (size_t)row * 1024 + k0;
    float4 v0 = *(const float4*)src;
    float4 v1 = *(const float4*)(src + 4);
    short8 o;
    o[0] = (short)f2bf(v0.x); o[1] = (short)f2bf(v0.y);
    o[2] = (short)f2bf(v0.z); o[3] = (short)f2bf(v0.w);
    o[4] = (short)f2bf(v1.x); o[5] = (short)f2bf(v1.y);
    o[6] = (short)f2bf(v1.z); o[7] = (short)f2bf(v1.w);
    *(short8*)(WhT + (size_t)P * 1024 + k0) = o;
}

// W1 (512x512 row-major [j][k]) -> W1t[k][j]  (fp32, head stays fp32)
__global__ __launch_bounds__(256) void transpose512(const float* __restrict__ W1,
                                                    float* __restrict__ W1t) {
    __shared__ float tile[64][65];
    int jb = blockIdx.x * 64, kb = blockIdx.y * 64;
    int t = threadIdx.x;
    #pragma unroll
    for (int i = 0; i < 16; ++i) {
        int idx = t + i * 256;
        int lj = idx >> 6, lk = idx & 63;
        tile[lj][lk] = W1[(jb + lj) * 512 + kb + lk];
    }
    __syncthreads();
    #pragma unroll
    for (int i = 0; i < 16; ++i) {
        int idx = t + i * 256;
        int lk = idx >> 6, lj = idx & 63;
        W1t[(kb + lk) * 512 + jb + lj] = tile[lj][lk];
    }
}

// Per-node metadata for all 511 processed nodes x 64 batch:
// tyv[node*64+b], alphaf[node*64+b] = is_int ? arg - emb[ty][511] : 0.
// Also W2t[k][op].
__global__ __launch_bounds__(256) void prep_nodes(
    const int* __restrict__ node_types, const float* __restrict__ node_args,
    const float* __restrict__ emb, const float* __restrict__ W2,
    float* __restrict__ W2t, int* __restrict__ tyv, float* __restrict__ alphaf) {
    int gid = blockIdx.x * 256 + threadIdx.x;  // 128 blocks -> 32768
    if (gid < 32704) {
        int node = gid >> 6, b = gid & 63;
        int ty = node_types[b * Nn + node];
        tyv[gid] = ty;
        alphaf[gid] = (ty <= 1) ? (node_args[b * Nn + node] - emb[ty * 512 + 511]) : 0.f;
    }
    if (gid < 8192) {
        int k = gid >> 4, op = gid & 15;
        W2t[gid] = W2[op * 512 + k];
    }
}

// E32b[ty][P] = dot(emb[ty][:], W_ih[row(P)][:]) + b_ih[row] + b_hh[row]  (fp32)
// w511f[P] = W_ih[row(P)][511]
__global__ __launch_bounds__(256) void e32_kernel(
    const float* __restrict__ emb, const float* __restrict__ W_ih,
    const float* __restrict__ b_ih, const float* __restrict__ b_hh,
    float* __restrict__ E32b, float* __restrict__ w511f) {
    int o = blockIdx.x * 256 + threadIdx.x;  // 256 blocks -> 65536 = 32*2048
    int ty = o >> 11, P = o & 2047;
    int row = ((P >> 4) & 3) * 1024 + (P >> 6) * 16 + (P & 15);
    const float* er = emb + (size_t)ty * 512;
    const float* wr = W_ih + (size_t)row * 512;
    float s = b_ih[row] + b_hh[row];
    for (int k = 0; k < 512; k += 4) {
        float4 e4 = *(const float4*)(er + k);
        float4 w4 = *(const float4*)(wr + k);
        s = fmaf(e4.x, w4.x, fmaf(e4.y, w4.y, fmaf(e4.z, w4.z, fmaf(e4.w, w4.w, s))));
    }
    E32b[o] = s;
    if (ty == 0) w511f[P] = wr[511];
}

__global__ void zero_out(float* __restrict__ outp, int n) {
    int i = blockIdx.x * 256 + threadIdx.x;
    if (i < n) outp[i] = 0.f;
}

// ---------------------------------------------------------------------------
// Leaf level d=8 (children h=c=0): pure elementwise. 16384 rows x 512 j.
// gates = E32b[ty] + alpha*w511f; f-gate dead (c_child=0).
// ---------------------------------------------------------------------------
__global__ __launch_bounds__(256) void leaf_cell(
    const float* __restrict__ E32b, const float* __restrict__ w511f,
    const int* __restrict__ tyv, const float* __restrict__ alphaf,
    unsigned short* __restrict__ out_h, float* __restrict__ out_c) {
    int gid = blockIdx.x * 256 + threadIdx.x;  // 4096 blocks -> 1,048,576
    int r = gid >> 6;                           // row 0..16383 (l*64+b)
    int jc = (gid & 63) * 8;
    int l = r >> 6;
    int gn = 16320 + r;                         // (255+l)*64 + b
    int ty = tyv[gn];
    float al = alphaf[gn];
    const float* Er = E32b + (size_t)ty * 2048;
    short8 hv;
    float cv[8];
    #pragma unroll
    for (int jj = 0; jj < 8; ++jj) {
        int j = jc + jj;
        int Pb = (j >> 4) * 64 + (j & 15);
        float ig = Er[Pb]      + al * w511f[Pb];
        float gg = Er[Pb + 32] + al * w511f[Pb + 32];
        float og = Er[Pb + 48] + al * w511f[Pb + 48];
        float cn = sigf(ig) * tanhf(gg);
        float hn = sigf(og) * tanhf(cn);
        hv[jj] = (short)f2bf(hn);
        cv[jj] = cn;
    }
    *(short8*)(out_h + (size_t)r * 512 + jc) = hv;
    if ((l & 1) == 0) {
        size_t cr = ((size_t)((r >> 7) * 64 + (r & 63))) * 512 + jc;
        float4 c0 = {cv[0], cv[1], cv[2], cv[3]};
        float4 c1 = {cv[4], cv[5], cv[6], cv[7]};
        *(float4*)(out_c + cr) = c0;
        *(float4*)(out_c + cr + 4) = c1;
    }
}

// ---------------------------------------------------------------------------
// Inner level, bf16 MFMA, K=1024 (hL,hR only). Block: 128 rows x 128 P-cols,
// 4 waves (2x2), wave tile 64x64, BK=64 (16 k-tiles), 2-barrier loop,
// global_load_lds width-16. acc INIT = E32b[ty][P] + alpha*w511f[P]
// (emb contribution + bias, fp32-exact). c stored for even locals at local>>1.
// ---------------------------------------------------------------------------
__global__ __launch_bounds__(256) void lstm_mfma(
    const unsigned short* __restrict__ WhT, const float* __restrict__ E32b,
    const float* __restrict__ w511f,
    const int* __restrict__ tyv, const float* __restrict__ alphaf,
    const unsigned short* __restrict__ in_h, const float* __restrict__ in_c,
    unsigned short* __restrict__ out_h, float* __restrict__ out_c,
    int base, int nloc) {
    __shared__ __attribute__((aligned(16))) unsigned short AB[16384]; // A:8192, B:8192 shorts
    unsigned short* As = AB;
    unsigned short* Bs = AB + 8192;
    const int t = threadIdx.x;
    const int w = t >> 6, lane = t & 63;
    const int wr = w >> 1, wc = w & 1;
    const int lane15 = lane & 15, lg = lane >> 4;
    const int M = nloc * 64;
    const int brow0 = blockIdx.x * 128;
    const int bcol0 = blockIdx.y * 128;
    const int lanek16 = (lane & 7) * 16;

    // per-q staging base pointers
    const char* hA[4];
    const char* wB[4];
    #pragma unroll
    for (int q = 0; q < 4; ++q) {
        int m = w * 32 + q * 8 + (lane >> 3);
        int r = brow0 + m; if (r > M - 1) r = M - 1;
        int l = r >> 6, b = r & 63;
        hA[q] = (const char*)in_h + ((size_t)(l * 128 + b)) * 1024; // hL row (2l)*64+b
        int P = bcol0 + w * 32 + q * 8 + (lane >> 3);
        wB[q] = (const char*)WhT + (size_t)P * 2048;
    }

    // accumulator init: emb-part + bias (fp32-exact), rank-1 arg correction
    f32x4 acc[4][4];
    float w4[4];
    int P4[4];
    #pragma unroll
    for (int q = 0; q < 4; ++q) {
        P4[q] = bcol0 + wc * 64 + q * 16 + lane15;
        w4[q] = w511f[P4[q]];
    }
    #pragma unroll
    for (int mi = 0; mi < 4; ++mi) {
        #pragma unroll
        for (int reg = 0; reg < 4; ++reg) {
            int r = brow0 + wr * 64 + mi * 16 + lg * 4 + reg;
            if (r > M - 1) r = M - 1;
            int gn = base * 64 + r;
            int ty = tyv[gn];
            float al = alphaf[gn];
            const float* Er = E32b + (size_t)ty * 2048;
            #pragma unroll
            for (int q = 0; q < 4; ++q)
                acc[mi][q][reg] = Er[P4[q]] + al * w4[q];
        }
    }

    for (int kt = 0; kt < 16; ++kt) {
        int aoff = (kt < 8) ? kt * 128 : 65536 + (kt - 8) * 128;  // hL then hR
        #pragma unroll
        for (int q = 0; q < 4; ++q) {
            __builtin_amdgcn_global_load_lds(AS1(hA[q] + aoff + lanek16),
                                             AS3((char*)As + w * 4096 + q * 1024), 16, 0, 0);
            __builtin_amdgcn_global_load_lds(AS1(wB[q] + kt * 128 + lanek16),
                                             AS3((char*)Bs + w * 4096 + q * 1024), 16, 0, 0);
        }
        __syncthreads();   // drains vmcnt -> LDS ready
        #pragma unroll
        for (int ks = 0; ks < 2; ++ks) {
            short8 av[4], bv[4];
            #pragma unroll
            for (int mi = 0; mi < 4; ++mi)
                av[mi] = *(const short8*)(As + (wr * 64 + mi * 16 + lane15) * 64 + ks * 32 + lg * 8);
            #pragma unroll
            for (int q = 0; q < 4; ++q)
                bv[q] = *(const short8*)(Bs + (wc * 64 + q * 16 + lane15) * 64 + ks * 32 + lg * 8);
            #pragma unroll
            for (int mi = 0; mi < 4; ++mi)
                #pragma unroll
                for (int q = 0; q < 4; ++q)
                    acc[mi][q] = __builtin_amdgcn_mfma_f32_16x16x32_bf16(av[mi], bv[q], acc[mi][q], 0, 0, 0);
        }
        __syncthreads();   // all waves done reading before next stage overwrites
    }

    // epilogue: acc[mi][0..3] = i,f,g,o of column j (bias/emb already inside)
    const int j = (blockIdx.y * 2 + wc) * 16 + lane15;
    #pragma unroll
    for (int mi = 0; mi < 4; ++mi) {
        int rbase = brow0 + wr * 64 + mi * 16 + lg * 4;
        #pragma unroll
        for (int reg = 0; reg < 4; ++reg) {
            int r = rbase + reg;
            if (r < M) {
                float ig = acc[mi][0][reg];
                float fg = acc[mi][1][reg];
                float gg = acc[mi][2][reg];
                float og = acc[mi][3][reg];
                float cl = in_c[(size_t)r * 512 + j];
                float cn = sigf(fg) * cl + sigf(ig) * tanhf(gg);
                float hn = sigf(og) * tanhf(cn);
                out_h[(size_t)r * 512 + j] = f2bf(hn);
                if (((r >> 6) & 1) == 0)  // even local: store c at local>>1
                    out_c[((size_t)((r >> 7) * 64 + (r & 63))) * 512 + j] = cn;
            }
        }
    }
}

// ---------------------------------------------------------------------------
// Head: x = relu(root_h @ W1^T + b1); logits = x @ W2^T + b2 + log(vm);
// out = softmax(logits/3). One block per batch element. rootH is bf16.
// ---------------------------------------------------------------------------
__global__ __launch_bounds__(256) void head_kernel(
    const unsigned short* __restrict__ rootH, const float* __restrict__ W1t,
    const float* __restrict__ b1, const float* __restrict__ W2t,
    const float* __restrict__ b2, const float* __restrict__ vmask,
    float* __restrict__ outp) {
    __shared__ float rh[512];
    __shared__ float xs[512];
    __shared__ float part[16][17];
    int b = blockIdx.x, t = threadIdx.x;
    rh[t] = bf2f(rootH[b * 512 + t]);
    rh[t + 256] = bf2f(rootH[b * 512 + t + 256]);
    __syncthreads();
    #pragma unroll
    for (int jj = 0; jj < 2; ++jj) {
        int j = t + jj * 256;
        float acc = b1[j];
        for (int k = 0; k < 512; ++k) acc = fmaf(rh[k], W1t[k * 512 + j], acc);
        xs[j] = fmaxf(acc, 0.f);
    }
    __syncthreads();
    int op = t & 15, seg = t >> 4;
    float p = 0.f;
    for (int k = seg * 32; k < seg * 32 + 32; ++k) p = fmaf(xs[k], W2t[k * 16 + op], p);
    part[seg][op] = p;
    __syncthreads();
    if (t < 16) {
        float s = 0.f;
        #pragma unroll
        for (int g = 0; g < 16; ++g) s += part[g][t];
        float logit = s + b2[t] + logf(vmask[b * 16 + t]);
        float z = logit * (1.0f / 3.0f);
        float m = z;
        for (int off = 8; off; off >>= 1) m = fmaxf(m, __shfl_xor(m, off, 16));
        float e = __expf(z - m);
        float ssum = e;
        for (int off = 8; off; off >>= 1) ssum += __shfl_xor(ssum, off, 16);
        outp[b * 16 + t] = e / ssum;
    }
}

extern "C" void kernel_launch(void* const* d_in, const int* in_sizes, int n_in,
                              void* d_out, int out_size, void* d_ws, size_t ws_size,
                              hipStream_t stream) {
    const int*   node_types = (const int*)d_in[0];
    const float* node_args  = (const float*)d_in[1];
    const float* vmask      = (const float*)d_in[2];
    const float* emb_table  = (const float*)d_in[3];
    const float* W_ih       = (const float*)d_in[4];
    const float* W_hh       = (const float*)d_in[5];
    const float* b_ih       = (const float*)d_in[6];
    const float* b_hh       = (const float*)d_in[7];
    const float* W1         = (const float*)d_in[8];
    const float* b1         = (const float*)d_in[9];
    const float* W2         = (const float*)d_in[10];
    const float* b2         = (const float*)d_in[11];
    float* out = (float*)d_out;

    char* ws = (char*)d_ws;
    size_t off = 0;
    auto alloc = [&](size_t bytes) { char* p = ws + off; off += (bytes + 255) & ~(size_t)255; return p; };
    unsigned short* WhT  = (unsigned short*)alloc((size_t)2048 * 1024 * 2);   // 4 MB
    float* E32b          = (float*)alloc((size_t)32 * 2048 * 4);              // 256 KB
    float* w511f         = (float*)alloc(2048 * 4);
    float* W1t           = (float*)alloc((size_t)512 * 512 * 4);              // 1 MB
    float* W2t           = (float*)alloc(8192 * 4);
    int*   tyv           = (int*)alloc(32704 * 4);
    float* alphaf        = (float*)alloc(32704 * 4);
    unsigned short* Xh   = (unsigned short*)alloc((size_t)256 * 64 * 512 * 2); // 16.8 MB
    unsigned short* Yh   = (unsigned short*)alloc((size_t)128 * 64 * 512 * 2); //  8.4 MB
    float* Xc            = (float*)alloc((size_t)128 * 64 * 512 * 4);          // 16.8 MB
    float* Yc            = (float*)alloc((size_t)64 * 64 * 512 * 4);           //  8.4 MB

    if (ws_size < off) {
        zero_out<<<(out_size + 255) / 256, 256, 0, stream>>>(out, out_size);
        return;
    }

    pack_whT<<<1024, 256, 0, stream>>>(W_hh, WhT);
    transpose512<<<dim3(8, 8), 256, 0, stream>>>(W1, W1t);
    prep_nodes<<<128, 256, 0, stream>>>(node_types, node_args, emb_table, W2, W2t, tyv, alphaf);
    e32_kernel<<<256, 256, 0, stream>>>(emb_table, W_ih, b_ih, b_hh, E32b, w511f);

    // leaf level d=8: pure elementwise (children are zero)
    leaf_cell<<<4096, 256, 0, stream>>>(E32b, w511f, tyv, alphaf, Xh, Xc);

    for (int d = 7; d >= 0; --d) {
        int nloc = 1 << d;
        unsigned short* oh = (d & 1) ? Yh : Xh;
        float* oc          = (d & 1) ? Yc : Xc;
        const unsigned short* ih = (d & 1) ? Xh : Yh;
        const float* ic          = (d & 1) ? Xc : Yc;
        int gx = (nloc >= 2) ? (nloc / 2) : 1;
        lstm_mfma<<<dim3(gx, 16), 256, 0, stream>>>(
            WhT, E32b, w511f, tyv, alphaf, ih, ic, oh, oc, nloc - 1, nloc);
    }

    head_kernel<<<64, 256, 0, stream>>>(Xh, W1t, b1, W2t, b2, vmask, out);
}

// Round 5
// 444.176 us; speedup vs baseline: 6.7505x; 1.1574x over previous
//
#include <hip/hip_runtime.h>
#include <math.h>

#define Nn 1023

typedef __attribute__((ext_vector_type(8))) short short8;
typedef __attribute__((ext_vector_type(4))) float f32x4;

#define AS1(p) ((const __attribute__((address_space(1))) void*)(p))
#define AS3(p) ((__attribute__((address_space(3))) void*)(p))

__device__ __forceinline__ float sigf(float x) { return 1.0f / (1.0f + __expf(-x)); }
__device__ __forceinline__ unsigned short f2bf(float x) {
    unsigned u = __float_as_uint(x);
    return (unsigned short)((u + 0x7fffu + ((u >> 16) & 1u)) >> 16);
}
__device__ __forceinline__ float bf2f(unsigned short b) {
    return __uint_as_float(((unsigned)b) << 16);
}

// ---------------------------------------------------------------------------
// Weight pack (hh part only): WhT[P][k2] bf16, P = jhi*64 + q*16 + jlo,
// orig gate row = q*1024 + (jhi*16+jlo); k2 in [0,1024) -> W_hh[row][k2].
// ---------------------------------------------------------------------------
__global__ __launch_bounds__(256) void pack_whT(const float* __restrict__ W_hh,
                                                unsigned short* __restrict__ WhT) {
    int idx = blockIdx.x * 256 + threadIdx.x;   // 1024 blocks
    int P = idx >> 7;
    int k0 = (idx & 127) * 8;
    int row = ((P >> 4) & 3) * 1024 + (P >> 6) * 16 + (P & 15);
    const float* src = W_hh + (size_t)row * 1024 + k0;
    float4 v0 = *(const float4*)src;
    float4 v1 = *(const float4*)(src + 4);
    short8 o;
    o[0] = (short)f2bf(v0.x); o[1] = (short)f2bf(v0.y);
    o[2] = (short)f2bf(v0.z); o[3] = (short)f2bf(v0.w);
    o[4] = (short)f2bf(v1.x); o[5] = (short)f2bf(v1.y);
    o[6] = (short)f2bf(v1.z); o[7] = (short)f2bf(v1.w);
    *(short8*)(WhT + (size_t)P * 1024 + k0) = o;
}

// W1 (512x512 row-major [j][k]) -> W1t[k][j]
__global__ __launch_bounds__(256) void transpose512(const float* __restrict__ W1,
                                                    float* __restrict__ W1t) {
    __shared__ float tile[64][65];
    int jb = blockIdx.x * 64, kb = blockIdx.y * 64;
    int t = threadIdx.x;
    #pragma unroll
    for (int i = 0; i < 16; ++i) {
        int idx = t + i * 256;
        int lj = idx >> 6, lk = idx & 63;
        tile[lj][lk] = W1[(jb + lj) * 512 + kb + lk];
    }
    __syncthreads();
    #pragma unroll
    for (int i = 0; i < 16; ++i) {
        int idx = t + i * 256;
        int lk = idx >> 6, lj = idx & 63;
        W1t[(kb + lk) * 512 + jb + lj] = tile[lj][lk];
    }
}

// tyv[node*64+b], alphaf = is_int ? arg - emb[ty][511] : 0; W2t[k][op]
__global__ __launch_bounds__(256) void prep_nodes(
    const int* __restrict__ node_types, const float* __restrict__ node_args,
    const float* __restrict__ emb, const float* __restrict__ W2,
    float* __restrict__ W2t, int* __restrict__ tyv, float* __restrict__ alphaf) {
    int gid = blockIdx.x * 256 + threadIdx.x;  // 128 blocks
    if (gid < 32704) {
        int node = gid >> 6, b = gid & 63;
        int ty = node_types[b * Nn + node];
        tyv[gid] = ty;
        alphaf[gid] = (ty <= 1) ? (node_args[b * Nn + node] - emb[ty * 512 + 511]) : 0.f;
    }
    if (gid < 8192) {
        int k = gid >> 4, op = gid & 15;
        W2t[gid] = W2[op * 512 + k];
    }
}

// E32b[ty][P] = dot(emb[ty], W_ih[row(P)]) + b_ih + b_hh  (fp32); w511f[P]
__global__ __launch_bounds__(256) void e32_kernel(
    const float* __restrict__ emb, const float* __restrict__ W_ih,
    const float* __restrict__ b_ih, const float* __restrict__ b_hh,
    float* __restrict__ E32b, float* __restrict__ w511f) {
    int o = blockIdx.x * 256 + threadIdx.x;  // 256 blocks
    int ty = o >> 11, P = o & 2047;
    int row = ((P >> 4) & 3) * 1024 + (P >> 6) * 16 + (P & 15);
    const float* er = emb + (size_t)ty * 512;
    const float* wr = W_ih + (size_t)row * 512;
    float s = b_ih[row] + b_hh[row];
    for (int k = 0; k < 512; k += 4) {
        float4 e4 = *(const float4*)(er + k);
        float4 w4 = *(const float4*)(wr + k);
        s = fmaf(e4.x, w4.x, fmaf(e4.y, w4.y, fmaf(e4.z, w4.z, fmaf(e4.w, w4.w, s))));
    }
    E32b[o] = s;
    if (ty == 0) w511f[P] = wr[511];
}

// Hleaf[ty][j], Cleaf[ty][j]: leaf cell for alpha=0 (non-int). f-gate dead.
__global__ __launch_bounds__(256) void leaf_tables(
    const float* __restrict__ E32b,
    unsigned short* __restrict__ Hleaf, float* __restrict__ Cleaf) {
    int o = blockIdx.x * 256 + threadIdx.x;   // 64 blocks -> 16384 = 32*512
    int ty = o >> 9, j = o & 511;
    int Pb = (j >> 4) * 64 + (j & 15);
    const float* Er = E32b + (size_t)ty * 2048;
    float ig = Er[Pb], gg = Er[Pb + 32], og = Er[Pb + 48];
    float cn = sigf(ig) * tanhf(gg);
    float hn = sigf(og) * tanhf(cn);
    Hleaf[o] = f2bf(hn);
    Cleaf[o] = cn;
}

// Int leaves only (ty<=1, ~1/16): fill Hside[row][512] (all int leaves) and
// Cside[(l>>1)*64+b][512] (even locals). Wave per row -> uniform branch.
__global__ __launch_bounds__(256) void leaf_int(
    const float* __restrict__ E32b, const float* __restrict__ w511f,
    const int* __restrict__ tyv, const float* __restrict__ alphaf,
    unsigned short* __restrict__ Hside, float* __restrict__ Cside) {
    int r = blockIdx.x * 4 + (threadIdx.x >> 6);  // 4096 blocks -> 16384 rows
    int gn = 16320 + r;
    int ty = tyv[gn];
    if (ty > 1) return;
    float al = alphaf[gn];
    int l = r >> 6, b = r & 63;
    int jc = (threadIdx.x & 63) * 8;
    const float* Er = E32b + (size_t)ty * 2048;
    short8 hv;
    float cv[8];
    #pragma unroll
    for (int jj = 0; jj < 8; ++jj) {
        int j = jc + jj;
        int Pb = (j >> 4) * 64 + (j & 15);
        float ig = Er[Pb]      + al * w511f[Pb];
        float gg = Er[Pb + 32] + al * w511f[Pb + 32];
        float og = Er[Pb + 48] + al * w511f[Pb + 48];
        float cn = sigf(ig) * tanhf(gg);
        float hn = sigf(og) * tanhf(cn);
        hv[jj] = (short)f2bf(hn);
        cv[jj] = cn;
    }
    *(short8*)(Hside + (size_t)r * 512 + jc) = hv;
    if ((l & 1) == 0) {
        size_t cr = ((size_t)((l >> 1) * 64 + b)) * 512 + jc;
        float4 c0 = {cv[0], cv[1], cv[2], cv[3]};
        float4 c1 = {cv[4], cv[5], cv[6], cv[7]};
        *(float4*)(Cside + cr) = c0;
        *(float4*)(Cside + cr + 4) = c1;
    }
}

__global__ void zero_out(float* __restrict__ outp, int n) {
    int i = blockIdx.x * 256 + threadIdx.x;
    if (i < n) outp[i] = 0.f;
}

// ---------------------------------------------------------------------------
// Inner level, bf16 MFMA, K=1024 (hL,hR). Block: 128 rows x 128 P-cols,
// 4 waves (2x2), wave tile 64x64, BK=64, 2-barrier loop, global_load_lds w16.
// acc INIT = E32b[ty][P] + alpha*w511f[P] (fp32-exact emb+bias part).
// LEAFC: children are leaves -> A rows come from Hleaf[ty] (32KB table) or
// Hside (int leaves); c_left from Cleaf[tyL]/Cside.
// ---------------------------------------------------------------------------
template<bool LEAFC>
__global__ __launch_bounds__(256) void lstm_mfma(
    const unsigned short* __restrict__ WhT, const float* __restrict__ E32b,
    const float* __restrict__ w511f,
    const int* __restrict__ tyv, const float* __restrict__ alphaf,
    const unsigned short* __restrict__ in_h, const float* __restrict__ in_c,
    const unsigned short* __restrict__ Hleaf, const unsigned short* __restrict__ Hside,
    const float* __restrict__ Cleaf, const float* __restrict__ Cside,
    unsigned short* __restrict__ out_h, float* __restrict__ out_c,
    int base, int nloc) {
    __shared__ __attribute__((aligned(16))) unsigned short AB[16384];
    unsigned short* As = AB;
    unsigned short* Bs = AB + 8192;
    const int t = threadIdx.x;
    const int w = t >> 6, lane = t & 63;
    const int wr = w >> 1, wc = w & 1;
    const int lane15 = lane & 15, lg = lane >> 4;
    const int M = nloc * 64;
    const int brow0 = blockIdx.x * 128;
    const int bcol0 = blockIdx.y * 128;
    const int lanek8 = (lane & 7) * 8;   // ushort units

    // per-q staging base pointers (per-lane row)
    const unsigned short* baseL[4];
    const unsigned short* baseR[4];
    const unsigned short* wB[4];
    #pragma unroll
    for (int q = 0; q < 4; ++q) {
        int m = w * 32 + q * 8 + (lane >> 3);
        int r = brow0 + m; if (r > M - 1) r = M - 1;
        int lf = (r >> 6) * 128 + (r & 63);   // left-child h-row
        if (LEAFC) {
            int tyL = tyv[16320 + lf];
            int tyR = tyv[16320 + lf + 64];
            baseL[q] = (tyL <= 1) ? (Hside + (size_t)lf * 512)
                                  : (Hleaf + (size_t)tyL * 512);
            baseR[q] = (tyR <= 1) ? (Hside + (size_t)(lf + 64) * 512)
                                  : (Hleaf + (size_t)tyR * 512);
        } else {
            baseL[q] = in_h + (size_t)lf * 512;
            baseR[q] = baseL[q] + 64 * 512;
        }
        int P = bcol0 + w * 32 + q * 8 + (lane >> 3);
        wB[q] = WhT + (size_t)P * 1024;
    }

    // accumulator init: emb contribution + bias (fp32), rank-1 arg correction
    f32x4 acc[4][4];
    float w4[4];
    int P4[4];
    #pragma unroll
    for (int q = 0; q < 4; ++q) {
        P4[q] = bcol0 + wc * 64 + q * 16 + lane15;
        w4[q] = w511f[P4[q]];
    }
    #pragma unroll
    for (int mi = 0; mi < 4; ++mi) {
        #pragma unroll
        for (int reg = 0; reg < 4; ++reg) {
            int r = brow0 + wr * 64 + mi * 16 + lg * 4 + reg;
            if (r > M - 1) r = M - 1;
            int gn = base * 64 + r;
            int ty = tyv[gn];
            float al = alphaf[gn];
            const float* Er = E32b + (size_t)ty * 2048;
            #pragma unroll
            for (int q = 0; q < 4; ++q)
                acc[mi][q][reg] = Er[P4[q]] + al * w4[q];
        }
    }

    for (int kt = 0; kt < 16; ++kt) {
        #pragma unroll
        for (int q = 0; q < 4; ++q) {
            const unsigned short* s = (kt < 8) ? (baseL[q] + kt * 64)
                                               : (baseR[q] + (kt - 8) * 64);
            __builtin_amdgcn_global_load_lds(AS1(s + lanek8),
                                             AS3(As + w * 2048 + q * 512), 16, 0, 0);
            __builtin_amdgcn_global_load_lds(AS1(wB[q] + kt * 64 + lanek8),
                                             AS3(Bs + w * 2048 + q * 512), 16, 0, 0);
        }
        __syncthreads();
        #pragma unroll
        for (int ks = 0; ks < 2; ++ks) {
            short8 av[4], bv[4];
            #pragma unroll
            for (int mi = 0; mi < 4; ++mi)
                av[mi] = *(const short8*)(As + (wr * 64 + mi * 16 + lane15) * 64 + ks * 32 + lg * 8);
            #pragma unroll
            for (int q = 0; q < 4; ++q)
                bv[q] = *(const short8*)(Bs + (wc * 64 + q * 16 + lane15) * 64 + ks * 32 + lg * 8);
            #pragma unroll
            for (int mi = 0; mi < 4; ++mi)
                #pragma unroll
                for (int q = 0; q < 4; ++q)
                    acc[mi][q] = __builtin_amdgcn_mfma_f32_16x16x32_bf16(av[mi], bv[q], acc[mi][q], 0, 0, 0);
        }
        __syncthreads();
    }

    // epilogue: acc[mi][0..3] = i,f,g,o of column j
    const int j = (blockIdx.y * 2 + wc) * 16 + lane15;
    #pragma unroll
    for (int mi = 0; mi < 4; ++mi) {
        int rbase = brow0 + wr * 64 + mi * 16 + lg * 4;
        #pragma unroll
        for (int reg = 0; reg < 4; ++reg) {
            int r = rbase + reg;
            if (r < M) {
                float ig = acc[mi][0][reg];
                float fg = acc[mi][1][reg];
                float gg = acc[mi][2][reg];
                float og = acc[mi][3][reg];
                float cl;
                if (LEAFC) {
                    int lf = (r >> 6) * 128 + (r & 63);
                    int tyL = tyv[16320 + lf];
                    cl = (tyL <= 1) ? Cside[(size_t)r * 512 + j]
                                    : Cleaf[(size_t)tyL * 512 + j];
                } else {
                    cl = in_c[(size_t)r * 512 + j];
                }
                float cn = sigf(fg) * cl + sigf(ig) * tanhf(gg);
                float hn = sigf(og) * tanhf(cn);
                out_h[(size_t)r * 512 + j] = f2bf(hn);
                if (((r >> 6) & 1) == 0)
                    out_c[((size_t)((r >> 7) * 64 + (r & 63))) * 512 + j] = cn;
            }
        }
    }
}

// ---------------------------------------------------------------------------
// Head: x = relu(root_h @ W1^T + b1); logits = x @ W2^T + b2 + log(vm);
// out = softmax(logits/3). One block per batch element.
// ---------------------------------------------------------------------------
__global__ __launch_bounds__(256) void head_kernel(
    const unsigned short* __restrict__ rootH, const float* __restrict__ W1t,
    const float* __restrict__ b1, const float* __restrict__ W2t,
    const float* __restrict__ b2, const float* __restrict__ vmask,
    float* __restrict__ outp) {
    __shared__ float rh[512];
    __shared__ float xs[512];
    __shared__ float part[16][17];
    int b = blockIdx.x, t = threadIdx.x;
    rh[t] = bf2f(rootH[b * 512 + t]);
    rh[t + 256] = bf2f(rootH[b * 512 + t + 256]);
    __syncthreads();
    #pragma unroll
    for (int jj = 0; jj < 2; ++jj) {
        int j = t + jj * 256;
        float acc = b1[j];
        for (int k = 0; k < 512; ++k) acc = fmaf(rh[k], W1t[k * 512 + j], acc);
        xs[j] = fmaxf(acc, 0.f);
    }
    __syncthreads();
    int op = t & 15, seg = t >> 4;
    float p = 0.f;
    for (int k = seg * 32; k < seg * 32 + 32; ++k) p = fmaf(xs[k], W2t[k * 16 + op], p);
    part[seg][op] = p;
    __syncthreads();
    if (t < 16) {
        float s = 0.f;
        #pragma unroll
        for (int g = 0; g < 16; ++g) s += part[g][t];
        float logit = s + b2[t] + logf(vmask[b * 16 + t]);
        float z = logit * (1.0f / 3.0f);
        float m = z;
        for (int off = 8; off; off >>= 1) m = fmaxf(m, __shfl_xor(m, off, 16));
        float e = __expf(z - m);
        float ssum = e;
        for (int off = 8; off; off >>= 1) ssum += __shfl_xor(ssum, off, 16);
        outp[b * 16 + t] = e / ssum;
    }
}

extern "C" void kernel_launch(void* const* d_in, const int* in_sizes, int n_in,
                              void* d_out, int out_size, void* d_ws, size_t ws_size,
                              hipStream_t stream) {
    const int*   node_types = (const int*)d_in[0];
    const float* node_args  = (const float*)d_in[1];
    const float* vmask      = (const float*)d_in[2];
    const float* emb_table  = (const float*)d_in[3];
    const float* W_ih       = (const float*)d_in[4];
    const float* W_hh       = (const float*)d_in[5];
    const float* b_ih       = (const float*)d_in[6];
    const float* b_hh       = (const float*)d_in[7];
    const float* W1         = (const float*)d_in[8];
    const float* b1         = (const float*)d_in[9];
    const float* W2         = (const float*)d_in[10];
    const float* b2         = (const float*)d_in[11];
    float* out = (float*)d_out;

    char* ws = (char*)d_ws;
    size_t off = 0;
    auto alloc = [&](size_t bytes) { char* p = ws + off; off += (bytes + 255) & ~(size_t)255; return p; };
    unsigned short* WhT  = (unsigned short*)alloc((size_t)2048 * 1024 * 2);    // 4 MB
    float* E32b          = (float*)alloc((size_t)32 * 2048 * 4);               // 256 KB
    float* w511f         = (float*)alloc(2048 * 4);
    float* W1t           = (float*)alloc((size_t)512 * 512 * 4);               // 1 MB
    float* W2t           = (float*)alloc(8192 * 4);
    int*   tyv           = (int*)alloc(32704 * 4);
    float* alphaf        = (float*)alloc(32704 * 4);
    unsigned short* Hleaf= (unsigned short*)alloc((size_t)32 * 512 * 2);       // 32 KB
    float* Cleaf         = (float*)alloc((size_t)32 * 512 * 4);                // 64 KB
    unsigned short* Hside= (unsigned short*)alloc((size_t)16384 * 512 * 2);    // 16.8 MB (sparse)
    float* Cside         = (float*)alloc((size_t)8192 * 512 * 4);              // 16.8 MB (sparse)
    unsigned short* Xh   = (unsigned short*)alloc((size_t)8192 * 512 * 2);     // 8.4 MB
    unsigned short* Yh   = (unsigned short*)alloc((size_t)4096 * 512 * 2);     // 4.2 MB
    float* Xc            = (float*)alloc((size_t)4096 * 512 * 4);              // 8.4 MB
    float* Yc            = (float*)alloc((size_t)2048 * 512 * 4);              // 4.2 MB

    if (ws_size < off) {
        zero_out<<<(out_size + 255) / 256, 256, 0, stream>>>(out, out_size);
        return;
    }

    pack_whT<<<1024, 256, 0, stream>>>(W_hh, WhT);
    transpose512<<<dim3(8, 8), 256, 0, stream>>>(W1, W1t);
    prep_nodes<<<128, 256, 0, stream>>>(node_types, node_args, emb_table, W2, W2t, tyv, alphaf);
    e32_kernel<<<256, 256, 0, stream>>>(emb_table, W_ih, b_ih, b_hh, E32b, w511f);
    leaf_tables<<<64, 256, 0, stream>>>(E32b, Hleaf, Cleaf);
    leaf_int<<<4096, 256, 0, stream>>>(E32b, w511f, tyv, alphaf, Hside, Cside);

    // d=7: children are leaves (table-based A / c)
    lstm_mfma<true><<<dim3(64, 16), 256, 0, stream>>>(
        WhT, E32b, w511f, tyv, alphaf,
        nullptr, nullptr, Hleaf, Hside, Cleaf, Cside,
        Xh, Xc, 127, 128);

    for (int d = 6; d >= 0; --d) {
        int nloc = 1 << d;
        unsigned short* oh = (d & 1) ? Xh : Yh;
        float* oc          = (d & 1) ? Xc : Yc;
        const unsigned short* ih = (d & 1) ? Yh : Xh;
        const float* ic          = (d & 1) ? Yc : Xc;
        int gx = (nloc >= 2) ? (nloc / 2) : 1;
        lstm_mfma<false><<<dim3(gx, 16), 256, 0, stream>>>(
            WhT, E32b, w511f, tyv, alphaf, ih, ic,
            nullptr, nullptr, nullptr, nullptr,
            oh, oc, nloc - 1, nloc);
    }

    // root h was written by d=0 -> Yh
    head_kernel<<<64, 256, 0, stream>>>(Yh, W1t, b1, W2t, b2, vmask, out);
}

// Round 6
// 419.982 us; speedup vs baseline: 7.1394x; 1.0576x over previous
//
#include <hip/hip_runtime.h>
#include <math.h>

#define Nn 1023

typedef __attribute__((ext_vector_type(8))) short short8;
typedef __attribute__((ext_vector_type(4))) float f32x4;

#define AS1(p) ((const __attribute__((address_space(1))) void*)(p))
#define AS3(p) ((__attribute__((address_space(3))) void*)(p))

__device__ __forceinline__ float sigf(float x) { return 1.0f / (1.0f + __expf(-x)); }
__device__ __forceinline__ float tanhfast(float x) {
    float e = __expf(2.0f * x);
    return 1.0f - 2.0f / (e + 1.0f);
}
__device__ __forceinline__ unsigned short f2bf(float x) {
    unsigned u = __float_as_uint(x);
    return (unsigned short)((u + 0x7fffu + ((u >> 16) & 1u)) >> 16);
}
__device__ __forceinline__ float bf2f(unsigned short b) {
    return __uint_as_float(((unsigned)b) << 16);
}

// ---------------------------------------------------------------------------
// WhT[P][k2] bf16, P = jhi*64 + q*16 + jlo; gate row = q*1024 + (jhi*16+jlo).
// ---------------------------------------------------------------------------
__global__ __launch_bounds__(256) void pack_whT(const float* __restrict__ W_hh,
                                                unsigned short* __restrict__ WhT) {
    int idx = blockIdx.x * 256 + threadIdx.x;   // 1024 blocks
    int P = idx >> 7;
    int k0 = (idx & 127) * 8;
    int row = ((P >> 4) & 3) * 1024 + (P >> 6) * 16 + (P & 15);
    const float* src = W_hh + (size_t)row * 1024 + k0;
    float4 v0 = *(const float4*)src;
    float4 v1 = *(const float4*)(src + 4);
    short8 o;
    o[0] = (short)f2bf(v0.x); o[1] = (short)f2bf(v0.y);
    o[2] = (short)f2bf(v0.z); o[3] = (short)f2bf(v0.w);
    o[4] = (short)f2bf(v1.x); o[5] = (short)f2bf(v1.y);
    o[6] = (short)f2bf(v1.z); o[7] = (short)f2bf(v1.w);
    *(short8*)(WhT + (size_t)P * 1024 + k0) = o;
}

__global__ __launch_bounds__(256) void transpose512(const float* __restrict__ W1,
                                                    float* __restrict__ W1t) {
    __shared__ float tile[64][65];
    int jb = blockIdx.x * 64, kb = blockIdx.y * 64;
    int t = threadIdx.x;
    #pragma unroll
    for (int i = 0; i < 16; ++i) {
        int idx = t + i * 256;
        int lj = idx >> 6, lk = idx & 63;
        tile[lj][lk] = W1[(jb + lj) * 512 + kb + lk];
    }
    __syncthreads();
    #pragma unroll
    for (int i = 0; i < 16; ++i) {
        int idx = t + i * 256;
        int lk = idx >> 6, lj = idx & 63;
        W1t[(kb + lk) * 512 + jb + lj] = tile[lj][lk];
    }
}

__global__ __launch_bounds__(256) void prep_nodes(
    const int* __restrict__ node_types, const float* __restrict__ node_args,
    const float* __restrict__ emb, const float* __restrict__ W2,
    float* __restrict__ W2t, int* __restrict__ tyv, float* __restrict__ alphaf) {
    int gid = blockIdx.x * 256 + threadIdx.x;  // 128 blocks
    if (gid < 32704) {
        int node = gid >> 6, b = gid & 63;
        int ty = node_types[b * Nn + node];
        tyv[gid] = ty;
        alphaf[gid] = (ty <= 1) ? (node_args[b * Nn + node] - emb[ty * 512 + 511]) : 0.f;
    }
    if (gid < 8192) {
        int k = gid >> 4, op = gid & 15;
        W2t[gid] = W2[op * 512 + k];
    }
}

// E32b[ty][P] = dot(emb[ty], W_ih[row(P)]) + b_ih + b_hh  (fp32); w511f[P]
__global__ __launch_bounds__(256) void e32_kernel(
    const float* __restrict__ emb, const float* __restrict__ W_ih,
    const float* __restrict__ b_ih, const float* __restrict__ b_hh,
    float* __restrict__ E32b, float* __restrict__ w511f) {
    int o = blockIdx.x * 256 + threadIdx.x;  // 256 blocks
    int ty = o >> 11, P = o & 2047;
    int row = ((P >> 4) & 3) * 1024 + (P >> 6) * 16 + (P & 15);
    const float* er = emb + (size_t)ty * 512;
    const float* wr = W_ih + (size_t)row * 512;
    float s = b_ih[row] + b_hh[row];
    for (int k = 0; k < 512; k += 4) {
        float4 e4 = *(const float4*)(er + k);
        float4 w4 = *(const float4*)(wr + k);
        s = fmaf(e4.x, w4.x, fmaf(e4.y, w4.y, fmaf(e4.z, w4.z, fmaf(e4.w, w4.w, s))));
    }
    E32b[o] = s;
    if (ty == 0) w511f[P] = wr[511];
}

// Hleaf (bf16) + Hleaf_f (fp32) + Cleaf: leaf cell for alpha=0.
__global__ __launch_bounds__(256) void leaf_tables(
    const float* __restrict__ E32b,
    unsigned short* __restrict__ Hleaf, float* __restrict__ Hleaf_f,
    float* __restrict__ Cleaf) {
    int o = blockIdx.x * 256 + threadIdx.x;   // 64 blocks -> 16384 = 32*512
    int ty = o >> 9, j = o & 511;
    int Pb = (j >> 4) * 64 + (j & 15);
    const float* Er = E32b + (size_t)ty * 2048;
    float ig = Er[Pb], gg = Er[Pb + 32], og = Er[Pb + 48];
    float cn = sigf(ig) * tanhfast(gg);
    float hn = sigf(og) * tanhfast(cn);
    Hleaf[o] = f2bf(hn);
    Hleaf_f[o] = hn;
    Cleaf[o] = cn;
}

// Int leaves only (ty<=1): Hside[row][512], Cside for even locals.
__global__ __launch_bounds__(256) void leaf_int(
    const float* __restrict__ E32b, const float* __restrict__ w511f,
    const int* __restrict__ tyv, const float* __restrict__ alphaf,
    unsigned short* __restrict__ Hside, float* __restrict__ Cside) {
    int r = blockIdx.x * 4 + (threadIdx.x >> 6);  // 4096 blocks -> 16384 rows
    int gn = 16320 + r;
    int ty = tyv[gn];
    if (ty > 1) return;
    float al = alphaf[gn];
    int l = r >> 6, b = r & 63;
    int jc = (threadIdx.x & 63) * 8;
    const float* Er = E32b + (size_t)ty * 2048;
    short8 hv;
    float cv[8];
    #pragma unroll
    for (int jj = 0; jj < 8; ++jj) {
        int j = jc + jj;
        int Pb = (j >> 4) * 64 + (j & 15);
        float ig = Er[Pb]      + al * w511f[Pb];
        float gg = Er[Pb + 32] + al * w511f[Pb + 32];
        float og = Er[Pb + 48] + al * w511f[Pb + 48];
        float cn = sigf(ig) * tanhfast(gg);
        float hn = sigf(og) * tanhfast(cn);
        hv[jj] = (short)f2bf(hn);
        cv[jj] = cn;
    }
    *(short8*)(Hside + (size_t)r * 512 + jc) = hv;
    if ((l & 1) == 0) {
        size_t cr = ((size_t)((l >> 1) * 64 + b)) * 512 + jc;
        float4 c0 = {cv[0], cv[1], cv[2], cv[3]};
        float4 c1 = {cv[4], cv[5], cv[6], cv[7]};
        *(float4*)(Cside + cr) = c0;
        *(float4*)(Cside + cr + 4) = c1;
    }
}

// GL[ty][P] = sum_k W_hh[row(P)][k]      * Hleaf_f[ty][k]
// GR[ty][P] = sum_k W_hh[row(P)][512+k]  * Hleaf_f[ty][k]
// Also zeroes rowidx (8448) and cnt.
__global__ __launch_bounds__(256) void glgr_kernel(
    const float* __restrict__ W_hh, const float* __restrict__ Hleaf_f,
    float* __restrict__ GLt, float* __restrict__ GRt,
    int* __restrict__ rowidx, int* __restrict__ cnt) {
    int gid = blockIdx.x * 256 + threadIdx.x;  // 512 blocks -> 131072
    if (gid < 8448) rowidx[gid] = 0;
    if (gid == 8448) *cnt = 0;
    int side = gid >> 16, ty = (gid >> 11) & 31, P = gid & 2047;
    int row = ((P >> 4) & 3) * 1024 + (P >> 6) * 16 + (P & 15);
    const float* wr = W_hh + (size_t)row * 1024 + side * 512;
    const float* hr = Hleaf_f + (size_t)ty * 512;
    float s = 0.f;
    for (int k = 0; k < 512; k += 4) {
        float4 w4 = *(const float4*)(wr + k);
        float4 h4 = *(const float4*)(hr + k);
        s = fmaf(w4.x, h4.x, fmaf(w4.y, h4.y, fmaf(w4.z, h4.z, fmaf(w4.w, h4.w, s))));
    }
    if (side == 0) GLt[ty * 2048 + P] = s;
    else           GRt[ty * 2048 + P] = s;
}

// Flag d=7 rows with >=1 int-leaf child -> append to rowidx (order-free).
__global__ __launch_bounds__(256) void flag_k(
    const int* __restrict__ tyv, int* __restrict__ rowidx, int* __restrict__ cnt) {
    int r = blockIdx.x * 256 + threadIdx.x;  // 32 blocks -> 8192
    int lf = (r >> 6) * 128 + (r & 63);
    if (tyv[16320 + lf] <= 1 || tyv[16320 + lf + 64] <= 1) {
        int p = atomicAdd(cnt, 1);
        rowidx[p] = r;
    }
}

__global__ void zero_out(float* __restrict__ outp, int n) {
    int i = blockIdx.x * 256 + threadIdx.x;
    if (i < n) outp[i] = 0.f;
}

// ---------------------------------------------------------------------------
// d=7 via tables: gates = E32b[tyP] + aP*w511 + GL[tyL] + GR[tyR] (fp32 exact).
// Writes ALL 8192 rows; rows with int children are overwritten by the
// compacted GEMM afterwards (stream-ordered). Tables staged in LDS with
// bank-decorrelating strides (129 / 33).
// Block: 256 rows x 32 j-cols. Grid (32, 16).
// ---------------------------------------------------------------------------
__global__ __launch_bounds__(256) void d7_table_cell(
    const float* __restrict__ E32b, const float* __restrict__ GLt,
    const float* __restrict__ GRt, const float* __restrict__ Cleaf,
    const float* __restrict__ Cside, const float* __restrict__ w511f,
    const int* __restrict__ tyv, const float* __restrict__ alphaf,
    unsigned short* __restrict__ out_h, float* __restrict__ out_c) {
    __shared__ float Es[32][129];
    __shared__ float GLs[32][129];
    __shared__ float GRs[32][129];
    __shared__ float Cls[32][33];
    __shared__ float w5s[128];
    const int t = threadIdx.x;
    const int j0 = blockIdx.y * 32;
    const int r = blockIdx.x * 256 + t;

    for (int i = t; i < 32 * 128; i += 256) {
        int ty = i >> 7, pp = i & 127;
        int gp = ((j0 >> 4) + (pp >> 6)) * 64 + (pp & 63);
        Es[ty][pp]  = E32b[ty * 2048 + gp];
        GLs[ty][pp] = GLt[ty * 2048 + gp];
        GRs[ty][pp] = GRt[ty * 2048 + gp];
    }
    for (int i = t; i < 32 * 32; i += 256) {
        int ty = i >> 5, jl = i & 31;
        Cls[ty][jl] = Cleaf[ty * 512 + j0 + jl];
    }
    if (t < 128) w5s[t] = w511f[((j0 >> 4) + (t >> 6)) * 64 + (t & 63)];
    __syncthreads();

    int gn = 8128 + r;                       // d=7: base=127
    int tyP = tyv[gn];
    float aP = alphaf[gn];
    int lf = (r >> 6) * 128 + (r & 63);
    int tyL = tyv[16320 + lf];
    int tyR = tyv[16320 + lf + 64];
    bool intL = (tyL <= 1);
    bool evenl = (((r >> 6) & 1) == 0);
    size_t crow = ((size_t)((r >> 7) * 64 + (r & 63))) * 512;

    #pragma unroll
    for (int j8 = 0; j8 < 4; ++j8) {
        short8 hv;
        float cv[8];
        #pragma unroll
        for (int jj = 0; jj < 8; ++jj) {
            int jl = j8 * 8 + jj;
            int ppb = (jl >> 4) * 64 + (jl & 15);
            float ig = Es[tyP][ppb]      + aP * w5s[ppb]      + GLs[tyL][ppb]      + GRs[tyR][ppb];
            float fg = Es[tyP][ppb + 16] + aP * w5s[ppb + 16] + GLs[tyL][ppb + 16] + GRs[tyR][ppb + 16];
            float gg = Es[tyP][ppb + 32] + aP * w5s[ppb + 32] + GLs[tyL][ppb + 32] + GRs[tyR][ppb + 32];
            float og = Es[tyP][ppb + 48] + aP * w5s[ppb + 48] + GLs[tyL][ppb + 48] + GRs[tyR][ppb + 48];
            float cl = intL ? Cside[(size_t)r * 512 + j0 + jl] : Cls[tyL][jl];
            float cn = sigf(fg) * cl + sigf(ig) * tanhfast(gg);
            float hn = sigf(og) * tanhfast(cn);
            hv[jj] = (short)f2bf(hn);
            cv[jj] = cn;
        }
        *(short8*)(out_h + (size_t)r * 512 + j0 + j8 * 8) = hv;
        if (evenl) {
            float4 c0 = {cv[0], cv[1], cv[2], cv[3]};
            float4 c1 = {cv[4], cv[5], cv[6], cv[7]};
            *(float4*)(out_c + crow + j0 + j8 * 8) = c0;
            *(float4*)(out_c + crow + j0 + j8 * 8 + 4) = c1;
        }
    }
}

// ---------------------------------------------------------------------------
// MFMA level kernel. MODE 0: inner (h from in_h, c from in_c).
// MODE 1: leaf children (h from Hleaf/Hside, c from Cleaf/Cside).
// MODE 2: MODE 1 + row compaction via rowidx/cnt (d=7 int-child rows).
// Single-barrier double-buffered K-loop (stage(t+1) overlaps compute(t)).
// Dynamic LDS: 65536 B (2 x (A 16K + B 16K)).
// ---------------------------------------------------------------------------
template<int MODE>
__global__ __launch_bounds__(256) void lstm_mfma(
    const unsigned short* __restrict__ WhT, const float* __restrict__ E32b,
    const float* __restrict__ w511f,
    const int* __restrict__ tyv, const float* __restrict__ alphaf,
    const unsigned short* __restrict__ in_h, const float* __restrict__ in_c,
    const unsigned short* __restrict__ Hleaf, const unsigned short* __restrict__ Hside,
    const float* __restrict__ Cleaf, const float* __restrict__ Cside,
    const int* __restrict__ rowidx, const int* __restrict__ cnt,
    unsigned short* __restrict__ out_h, float* __restrict__ out_c,
    int base, int nloc) {
    extern __shared__ unsigned short AB[];   // 32768 ushorts = 64 KB
    const int t = threadIdx.x;
    const int w = t >> 6, lane = t & 63;
    const int wr = w >> 1, wc = w & 1;
    const int lane15 = lane & 15, lg = lane >> 4;
    const int M = nloc * 64;
    const int brow0 = blockIdx.x * 128;
    const int bcol0 = blockIdx.y * 128;
    const int lanek8 = (lane & 7) * 8;   // ushort units

    if (MODE == 2) {
        int nc = *cnt;
        int padded = (nc + 127) & ~127;
        if (brow0 >= padded) return;
    }

    // per-q staging base pointers (per-lane row)
    const unsigned short* baseL[4];
    const unsigned short* baseR[4];
    const unsigned short* wB[4];
    #pragma unroll
    for (int q = 0; q < 4; ++q) {
        int m = w * 32 + q * 8 + (lane >> 3);
        int r = brow0 + m;
        if (MODE == 2) r = rowidx[r];
        else if (r > M - 1) r = M - 1;
        int lf = (r >> 6) * 128 + (r & 63);   // left-child h-row
        if (MODE >= 1) {
            int tyL = tyv[16320 + lf];
            int tyR = tyv[16320 + lf + 64];
            baseL[q] = (tyL <= 1) ? (Hside + (size_t)lf * 512)
                                  : (Hleaf + (size_t)tyL * 512);
            baseR[q] = (tyR <= 1) ? (Hside + (size_t)(lf + 64) * 512)
                                  : (Hleaf + (size_t)tyR * 512);
        } else {
            baseL[q] = in_h + (size_t)lf * 512;
            baseR[q] = baseL[q] + 64 * 512;
        }
        int P = bcol0 + w * 32 + q * 8 + (lane >> 3);
        wB[q] = WhT + (size_t)P * 1024;
    }

    auto stage = [&](int kt, int cur) {
        unsigned short* Ad = AB + cur * 16384;
        unsigned short* Bd = Ad + 8192;
        #pragma unroll
        for (int q = 0; q < 4; ++q) {
            const unsigned short* s = (kt < 8) ? (baseL[q] + kt * 64)
                                               : (baseR[q] + (kt - 8) * 64);
            __builtin_amdgcn_global_load_lds(AS1(s + lanek8),
                                             AS3(Ad + w * 2048 + q * 512), 16, 0, 0);
            __builtin_amdgcn_global_load_lds(AS1(wB[q] + kt * 64 + lanek8),
                                             AS3(Bd + w * 2048 + q * 512), 16, 0, 0);
        }
    };

    stage(0, 0);

    // accumulator init: emb contribution + bias (fp32), rank-1 arg correction
    f32x4 acc[4][4];
    float w4[4];
    int P4[4];
    int rr[4][4];
    #pragma unroll
    for (int q = 0; q < 4; ++q) {
        P4[q] = bcol0 + wc * 64 + q * 16 + lane15;
        w4[q] = w511f[P4[q]];
    }
    #pragma unroll
    for (int mi = 0; mi < 4; ++mi) {
        #pragma unroll
        for (int reg = 0; reg < 4; ++reg) {
            int r = brow0 + wr * 64 + mi * 16 + lg * 4 + reg;
            if (MODE == 2) r = rowidx[r];
            else if (r > M - 1) r = M - 1;
            rr[mi][reg] = r;
            int gn = base * 64 + r;
            int ty = tyv[gn];
            float al = alphaf[gn];
            const float* Er = E32b + (size_t)ty * 2048;
            #pragma unroll
            for (int q = 0; q < 4; ++q)
                acc[mi][q][reg] = Er[P4[q]] + al * w4[q];
        }
    }

    int cur = 0;
    for (int kt = 0; kt < 16; ++kt) {
        __syncthreads();                    // buf[cur] staged; prev reads done
        if (kt < 15) stage(kt + 1, cur ^ 1);
        const unsigned short* Ac = AB + cur * 16384;
        const unsigned short* Bc = Ac + 8192;
        #pragma unroll
        for (int ks = 0; ks < 2; ++ks) {
            short8 av[4], bv[4];
            #pragma unroll
            for (int mi = 0; mi < 4; ++mi)
                av[mi] = *(const short8*)(Ac + (wr * 64 + mi * 16 + lane15) * 64 + ks * 32 + lg * 8);
            #pragma unroll
            for (int q = 0; q < 4; ++q)
                bv[q] = *(const short8*)(Bc + (wc * 64 + q * 16 + lane15) * 64 + ks * 32 + lg * 8);
            #pragma unroll
            for (int mi = 0; mi < 4; ++mi)
                #pragma unroll
                for (int q = 0; q < 4; ++q)
                    acc[mi][q] = __builtin_amdgcn_mfma_f32_16x16x32_bf16(av[mi], bv[q], acc[mi][q], 0, 0, 0);
        }
        cur ^= 1;
    }

    // epilogue: acc[mi][0..3] = i,f,g,o of column j
    const int j = (blockIdx.y * 2 + wc) * 16 + lane15;
    #pragma unroll
    for (int mi = 0; mi < 4; ++mi) {
        #pragma unroll
        for (int reg = 0; reg < 4; ++reg) {
            int r = rr[mi][reg];
            if (r < M) {
                float ig = acc[mi][0][reg];
                float fg = acc[mi][1][reg];
                float gg = acc[mi][2][reg];
                float og = acc[mi][3][reg];
                float cl;
                if (MODE >= 1) {
                    int lf = (r >> 6) * 128 + (r & 63);
                    int tyL = tyv[16320 + lf];
                    cl = (tyL <= 1) ? Cside[(size_t)r * 512 + j]
                                    : Cleaf[(size_t)tyL * 512 + j];
                } else {
                    cl = in_c[(size_t)r * 512 + j];
                }
                float cn = sigf(fg) * cl + sigf(ig) * tanhfast(gg);
                float hn = sigf(og) * tanhfast(cn);
                out_h[(size_t)r * 512 + j] = f2bf(hn);
                if (((r >> 6) & 1) == 0)
                    out_c[((size_t)((r >> 7) * 64 + (r & 63))) * 512 + j] = cn;
            }
        }
    }
}

// ---------------------------------------------------------------------------
// Head: x = relu(root_h @ W1^T + b1); logits = x @ W2^T + b2 + log(vm);
// out = softmax(logits/3). One block per batch element.
// ---------------------------------------------------------------------------
__global__ __launch_bounds__(256) void head_kernel(
    const unsigned short* __restrict__ rootH, const float* __restrict__ W1t,
    const float* __restrict__ b1, const float* __restrict__ W2t,
    const float* __restrict__ b2, const float* __restrict__ vmask,
    float* __restrict__ outp) {
    __shared__ float rh[512];
    __shared__ float xs[512];
    __shared__ float part[16][17];
    int b = blockIdx.x, t = threadIdx.x;
    rh[t] = bf2f(rootH[b * 512 + t]);
    rh[t + 256] = bf2f(rootH[b * 512 + t + 256]);
    __syncthreads();
    #pragma unroll
    for (int jj = 0; jj < 2; ++jj) {
        int j = t + jj * 256;
        float acc = b1[j];
        for (int k = 0; k < 512; ++k) acc = fmaf(rh[k], W1t[k * 512 + j], acc);
        xs[j] = fmaxf(acc, 0.f);
    }
    __syncthreads();
    int op = t & 15, seg = t >> 4;
    float p = 0.f;
    for (int k = seg * 32; k < seg * 32 + 32; ++k) p = fmaf(xs[k], W2t[k * 16 + op], p);
    part[seg][op] = p;
    __syncthreads();
    if (t < 16) {
        float s = 0.f;
        #pragma unroll
        for (int g = 0; g < 16; ++g) s += part[g][t];
        float logit = s + b2[t] + logf(vmask[b * 16 + t]);
        float z = logit * (1.0f / 3.0f);
        float m = z;
        for (int off = 8; off; off >>= 1) m = fmaxf(m, __shfl_xor(m, off, 16));
        float e = __expf(z - m);
        float ssum = e;
        for (int off = 8; off; off >>= 1) ssum += __shfl_xor(ssum, off, 16);
        outp[b * 16 + t] = e / ssum;
    }
}

extern "C" void kernel_launch(void* const* d_in, const int* in_sizes, int n_in,
                              void* d_out, int out_size, void* d_ws, size_t ws_size,
                              hipStream_t stream) {
    const int*   node_types = (const int*)d_in[0];
    const float* node_args  = (const float*)d_in[1];
    const float* vmask      = (const float*)d_in[2];
    const float* emb_table  = (const float*)d_in[3];
    const float* W_ih       = (const float*)d_in[4];
    const float* W_hh       = (const float*)d_in[5];
    const float* b_ih       = (const float*)d_in[6];
    const float* b_hh       = (const float*)d_in[7];
    const float* W1         = (const float*)d_in[8];
    const float* b1         = (const float*)d_in[9];
    const float* W2         = (const float*)d_in[10];
    const float* b2         = (const float*)d_in[11];
    float* out = (float*)d_out;

    char* ws = (char*)d_ws;
    size_t off = 0;
    auto alloc = [&](size_t bytes) { char* p = ws + off; off += (bytes + 255) & ~(size_t)255; return p; };
    unsigned short* WhT  = (unsigned short*)alloc((size_t)2048 * 1024 * 2);    // 4 MB
    float* E32b          = (float*)alloc((size_t)32 * 2048 * 4);
    float* w511f         = (float*)alloc(2048 * 4);
    float* W1t           = (float*)alloc((size_t)512 * 512 * 4);
    float* W2t           = (float*)alloc(8192 * 4);
    int*   tyv           = (int*)alloc(32704 * 4);
    float* alphaf        = (float*)alloc(32704 * 4);
    unsigned short* Hleaf= (unsigned short*)alloc((size_t)32 * 512 * 2);
    float* Hleaf_f       = (float*)alloc((size_t)32 * 512 * 4);
    float* Cleaf         = (float*)alloc((size_t)32 * 512 * 4);
    float* GLt           = (float*)alloc((size_t)32 * 2048 * 4);
    float* GRt           = (float*)alloc((size_t)32 * 2048 * 4);
    int*   rowidx        = (int*)alloc(8448 * 4);
    int*   cnt           = (int*)alloc(256);
    unsigned short* Hside= (unsigned short*)alloc((size_t)16384 * 512 * 2);    // 16.8 MB
    float* Cside         = (float*)alloc((size_t)8192 * 512 * 4);              // 16.8 MB
    unsigned short* Xh   = (unsigned short*)alloc((size_t)8192 * 512 * 2);     // 8.4 MB
    unsigned short* Yh   = (unsigned short*)alloc((size_t)4096 * 512 * 2);     // 4.2 MB
    float* Xc            = (float*)alloc((size_t)4096 * 512 * 4);              // 8.4 MB
    float* Yc            = (float*)alloc((size_t)2048 * 512 * 4);              // 4.2 MB

    if (ws_size < off) {
        zero_out<<<(out_size + 255) / 256, 256, 0, stream>>>(out, out_size);
        return;
    }

    pack_whT<<<1024, 256, 0, stream>>>(W_hh, WhT);
    transpose512<<<dim3(8, 8), 256, 0, stream>>>(W1, W1t);
    prep_nodes<<<128, 256, 0, stream>>>(node_types, node_args, emb_table, W2, W2t, tyv, alphaf);
    e32_kernel<<<256, 256, 0, stream>>>(emb_table, W_ih, b_ih, b_hh, E32b, w511f);
    leaf_tables<<<64, 256, 0, stream>>>(E32b, Hleaf, Hleaf_f, Cleaf);
    leaf_int<<<4096, 256, 0, stream>>>(E32b, w511f, tyv, alphaf, Hside, Cside);
    glgr_kernel<<<512, 256, 0, stream>>>(W_hh, Hleaf_f, GLt, GRt, rowidx, cnt);
    flag_k<<<32, 256, 0, stream>>>(tyv, rowidx, cnt);

    // d=7: table path for all rows, then compacted MFMA overwrite of
    // rows with int-leaf children (stream-ordered).
    d7_table_cell<<<dim3(32, 16), 256, 0, stream>>>(
        E32b, GLt, GRt, Cleaf, Cside, w511f, tyv, alphaf, Xh, Xc);
    lstm_mfma<2><<<dim3(64, 16), 256, 65536, stream>>>(
        WhT, E32b, w511f, tyv, alphaf,
        nullptr, nullptr, Hleaf, Hside, Cleaf, Cside,
        rowidx, cnt, Xh, Xc, 127, 128);

    for (int d = 6; d >= 0; --d) {
        int nloc = 1 << d;
        unsigned short* oh = (d & 1) ? Xh : Yh;
        float* oc          = (d & 1) ? Xc : Yc;
        const unsigned short* ih = (d & 1) ? Yh : Xh;
        const float* ic          = (d & 1) ? Yc : Xc;
        int gx = (nloc >= 2) ? (nloc / 2) : 1;
        lstm_mfma<0><<<dim3(gx, 16), 256, 65536, stream>>>(
            WhT, E32b, w511f, tyv, alphaf, ih, ic,
            nullptr, nullptr, nullptr, nullptr,
            nullptr, nullptr, oh, oc, nloc - 1, nloc);
    }

    // root h was written by d=0 -> Yh
    head_kernel<<<64, 256, 0, stream>>>(Yh, W1t, b1, W2t, b2, vmask, out);
}